// Round 8
// baseline (265.728 us; speedup 1.0000x reference)
//
#include <hip/hip_runtime.h>
#include <cstddef>

#define NSIDE_ 128
#define NLAT_  511
#define NLON_  512
#define LMAX_  511
#define MMAX_  257
#define NPIX_  196608
#define TWO_PI_ 6.28318530717958647692f

#define XELEMS_   16809856u   // 511*257*128 floats (X, f32, [k][m][rb])
#define X2TELEMS_ 16842752u   // 257*128*512 ushorts (x2T bf16, [m][rb][l])
#define TELEMS_   557056u     // 2*512*544 ushorts (belt trig table)

typedef __attribute__((ext_vector_type(8))) short bf16x8;
typedef __attribute__((ext_vector_type(4))) float f32x4;

static __device__ __forceinline__ unsigned short f2bf(float f) {
    union { float f; unsigned int u; } v; v.f = f;
    unsigned int r = v.u + 0x7FFFu + ((v.u >> 16) & 1u);   // RNE
    return (unsigned short)(r >> 16);
}

static __device__ __forceinline__ unsigned int cvtpk(float lo, float hi) {
    unsigned int d;
    asm("v_cvt_pk_bf16_f32 %0, %1, %2" : "=v"(d) : "v"(lo), "v"(hi));
    return d;
}

static __device__ __forceinline__ bf16x8 ld_pair(const unsigned int* p) {
    union { struct { uint2 a, b; } s; bf16x8 v; } t;
    t.s.a = *(const uint2*)p;
    t.s.b = *(const uint2*)(p + 2);
    return t.v;
}

// ---------------------------------------------------------------------------
// K0: pack x[b][l][m][ri] (f32) -> x2T[m][rb][l] (bf16), rb = ri*64+b,
// l zero-padded to 512.  (round-5 verbatim)
// ---------------------------------------------------------------------------
__global__ __launch_bounds__(256) void pack_x_k(
    const float* __restrict__ x, unsigned short* __restrict__ x2T)
{
    __shared__ unsigned short lds[32][520];
    int b   = blockIdx.x;
    int l0  = blockIdx.y * 32;
    int tid = threadIdx.x;

    const float* src = x + ((size_t)b * LMAX_ + l0) * (2 * MMAX_);
    for (int li = 0; li < 32; ++li) {
        bool valid = (l0 + li) < LMAX_;
        for (int m2 = tid; m2 < 2 * MMAX_; m2 += 256) {
            float f = valid ? src[(size_t)li * (2 * MMAX_) + m2] : 0.f;
            lds[li][m2] = f2bf(f);
        }
    }
    __syncthreads();

    for (int m2 = tid; m2 < 2 * MMAX_; m2 += 256) {
        int m  = m2 >> 1;
        int rb = (m2 & 1) * 64 + b;
        unsigned short* dst = x2T + ((size_t)m * 128 + rb) * 512 + l0;
#pragma unroll
        for (int g = 0; g < 4; ++g) {
            unsigned int w0 = (unsigned int)lds[g*8+0][m2] | ((unsigned int)lds[g*8+1][m2] << 16);
            unsigned int w1 = (unsigned int)lds[g*8+2][m2] | ((unsigned int)lds[g*8+3][m2] << 16);
            unsigned int w2 = (unsigned int)lds[g*8+4][m2] | ((unsigned int)lds[g*8+5][m2] << 16);
            unsigned int w3 = (unsigned int)lds[g*8+6][m2] | ((unsigned int)lds[g*8+7][m2] << 16);
            *(uint4*)(dst + g * 8) = make_uint4(w0, w1, w2, w3);
        }
    }
}

// ---------------------------------------------------------------------------
// K0b: belt trig table T[p][j][kappa] bf16; p=0 -> off=0.5, p=1 -> off=0.
// dword m = (cos m*th, -sin m*th); zero for m >= 257.  (~3 us)
// ---------------------------------------------------------------------------
__global__ __launch_bounds__(256) void trig_k(unsigned short* __restrict__ T)
{
    int id = blockIdx.x * 256 + threadIdx.x;   // 0..1023
    int p  = id >> 9, j = id & 511;
    float off = p ? 0.f : 0.5f;
    float theta = TWO_PI_ * ((float)j + off) / 512.f;
    float dc, ds;
    sincosf(theta, &ds, &dc);
    float cs = 1.f, sn = 0.f;
    unsigned int* row = (unsigned int*)(T + ((size_t)p * 512 + j) * 544);
    for (int m = 0; m < 272; ++m) {
        row[m] = (m < MMAX_) ? cvtpk(cs, -sn) : 0u;
        float cn = fmaf(cs, dc, -(sn * ds));
        float s2 = fmaf(sn, dc,  cs * ds);
        cs = cn; sn = s2;
    }
}

// ---------------------------------------------------------------------------
// K1: Legendre MFMA (round-5 verbatim): 1 barrier/step, dbuf LDS,
// depth-1 prefetch of pct rows + B-fragments.
// ---------------------------------------------------------------------------
__global__ __launch_bounds__(256, 3) void legendre5_k(
    const unsigned short* __restrict__ x2T,
    const float* __restrict__ pct,
    float* __restrict__ X)
{
    __shared__ __align__(16) unsigned int Apk[2][128 * 18];

    int bid = blockIdx.x;
    int xcd = bid & 7, n = bid >> 3;
    int kt = n & 3, mi = n >> 2;
    int m = mi * 8 + xcd;
    if (m >= MMAX_) return;

    int k0  = kt * 128;
    int tid = threadIdx.x;
    int lane = tid & 63, w = tid >> 6;
    int wk = (w >> 1) * 64, wrb = (w & 1) * 64;
    int r = lane & 15, g = lane >> 4;

    const float* pctm = pct + (size_t)m * (LMAX_ * NLAT_);
    const unsigned short* x2m = x2T + (size_t)m * (128 * 512);

    int kc = tid & 15;
    int lp = tid >> 4;
    int o7 = (k0 + kc + 112 <= NLAT_ - 1) ? 112 : (NLAT_ - 1 - (k0 + kc));

    f32x4 acc[4][4];
#pragma unroll
    for (int a = 0; a < 4; ++a)
#pragma unroll
        for (int c = 0; c < 4; ++c) acc[a][c] = (f32x4){0.f, 0.f, 0.f, 0.f};

    float e0[8], e1[8];
    bf16x8 Bfc[4], Bfn[4];

    {
        const float* pa = pctm + (size_t)(2 * lp)     * NLAT_ + k0 + kc;
        const float* pb = pctm + (size_t)(2 * lp + 1) * NLAT_ + k0 + kc;
#pragma unroll
        for (int i = 0; i < 7; ++i) { e0[i] = pa[16 * i]; e1[i] = pb[16 * i]; }
        e0[7] = pa[o7]; e1[7] = pb[o7];
#pragma unroll
        for (int rs = 0; rs < 4; ++rs)
            Bfc[rs] = *(const bf16x8*)(x2m + (size_t)(wrb + rs * 16 + r) * 512 + g * 8);
    }

#pragma unroll 2
    for (int s = 0; s < 16; ++s) {
        const int bsel = s & 1;
        unsigned int* wp = &Apk[bsel][0];
#pragma unroll
        for (int i = 0; i < 8; ++i) {
            unsigned int dwv = cvtpk(e0[i], e1[i]);
            int kk = kc + 16 * i;
            wp[kk * 18 + (lp ^ ((i & 3) << 2))] = dwv;
        }
        __syncthreads();

        if (s < 15) {
            int l0n = (s + 1) * 32;
            int la = l0n + 2 * lp, lb = la + 1;
            if (lb > LMAX_ - 1) lb = LMAX_ - 1;
            const float* pa = pctm + (size_t)la * NLAT_ + k0 + kc;
            const float* pb = pctm + (size_t)lb * NLAT_ + k0 + kc;
#pragma unroll
            for (int i = 0; i < 7; ++i) { e0[i] = pa[16 * i]; e1[i] = pb[16 * i]; }
            e0[7] = pa[o7]; e1[7] = pb[o7];
            int lbase = l0n + g * 8;
#pragma unroll
            for (int rs = 0; rs < 4; ++rs)
                Bfn[rs] = *(const bf16x8*)(x2m + (size_t)(wrb + rs * 16 + r) * 512 + lbase);
        }

        const unsigned int* rp = &Apk[bsel][0];
        bf16x8 Af[4];
#pragma unroll
        for (int ks = 0; ks < 4; ++ks) {
            int row = wk + ks * 16 + r;
            Af[ks] = ld_pair(rp + row * 18 + ((g * 4) ^ ((ks & 3) << 2)));
        }
#pragma unroll
        for (int ks = 0; ks < 4; ++ks)
#pragma unroll
            for (int rs = 0; rs < 4; ++rs)
                acc[ks][rs] = __builtin_amdgcn_mfma_f32_16x16x32_bf16(
                    Af[ks], Bfc[rs], acc[ks][rs], 0, 0, 0);

        if (s < 15) {
#pragma unroll
            for (int rs = 0; rs < 4; ++rs) Bfc[rs] = Bfn[rs];
        }
    }

    float wgt = (m == 0) ? 1.f : 2.f;
#pragma unroll
    for (int ks = 0; ks < 4; ++ks) {
#pragma unroll
        for (int rs = 0; rs < 4; ++rs) {
            int rb = wrb + rs * 16 + r;
#pragma unroll
            for (int i = 0; i < 4; ++i) {
                int k = k0 + wk + ks * 16 + g * 4 + i;
                if (k < NLAT_)
                    X[((size_t)k * MMAX_ + m) * 128 + rb] = acc[ks][rs][i] * wgt;
            }
        }
    }
}

// ---------------------------------------------------------------------------
// K2a: belt synthesis (rings 127..383, nphi=512). A-fragments direct from
// the trig table (kappa-contiguous 16B loads, dbuf); no trig VALU, no A-LDS.
// B staged in LDS exactly as round 5.
// ---------------------------------------------------------------------------
__global__ __launch_bounds__(256, 3) void synth_belt_k(
    const float* __restrict__ X,
    const unsigned short* __restrict__ T,
    float* __restrict__ out)
{
    __shared__ __align__(16) unsigned int Bdw[2][64 * 18];

    int k    = 127 + blockIdx.x;              // 127..383
    int jblk = blockIdx.y * 256;
    int start = 2 * (NSIDE_ - 1) * NSIDE_ + (k - (NSIDE_ - 1)) * 512;
    int p = (k - 127) & 1;                    // off: p=0 -> 0.5, p=1 -> 0

    int tid  = threadIdx.x;
    int lane = tid & 63, w = tid >> 6;
    int r = lane & 15, g = lane >> 4;

    int bb = tid & 63, kq = tid >> 6;
    const float* Xk = X + (size_t)k * (MMAX_ * 128) + bb;
    const unsigned short* Tp = T + (size_t)p * (512 * 544);
    int swzB = ((bb >> 4) & 3) << 2;

    auto load_bv = [&](int step, float* bv) {
        int kap0 = step * 32 + kq * 8;
#pragma unroll
        for (int i = 0; i < 8; ++i) {
            int kap = kap0 + i, mm = kap >> 1;
            bv[i] = (mm < MMAX_) ? Xk[(size_t)mm * 128 + (kap & 1) * 64] : 0.f;
        }
    };
    auto load_A = [&](int step, bf16x8* dst) {
        int cb = step * 32 + g * 8;
#pragma unroll
        for (int ks = 0; ks < 4; ++ks) {
            int row = jblk + w * 64 + ks * 16 + r;
            dst[ks] = *(const bf16x8*)(Tp + (size_t)row * 544 + cb);
        }
    };

    float bv[8];
    unsigned int bdw[4];
    bf16x8 AfC[4], AfN[4];
    load_bv(0, bv);
    load_A(0, AfC);
#pragma unroll
    for (int q = 0; q < 4; ++q) bdw[q] = cvtpk(bv[2 * q], bv[2 * q + 1]);

    f32x4 acc[4][4];
#pragma unroll
    for (int a = 0; a < 4; ++a)
#pragma unroll
        for (int c = 0; c < 4; ++c) acc[a][c] = (f32x4){0.f, 0.f, 0.f, 0.f};

#pragma unroll 2
    for (int s = 0; s < 17; ++s) {
        const int bsel = s & 1;
        {
            unsigned int* bp = &Bdw[bsel][bb * 18];
            int cb = (kq * 4) ^ swzB;
            *(uint2*)(bp + cb)     = make_uint2(bdw[0], bdw[1]);
            *(uint2*)(bp + cb + 2) = make_uint2(bdw[2], bdw[3]);
        }
        __syncthreads();

        if (s < 16) { load_bv(s + 1, bv); load_A(s + 1, AfN); }

        const unsigned int* brp = &Bdw[bsel][0];
        bf16x8 Bf[4];
#pragma unroll
        for (int bs = 0; bs < 4; ++bs) {
            int row = bs * 16 + r;
            Bf[bs] = ld_pair(brp + row * 18 + ((g * 4) ^ ((bs & 3) << 2)));
        }
#pragma unroll
        for (int ks = 0; ks < 4; ++ks)
#pragma unroll
            for (int bs = 0; bs < 4; ++bs)
                acc[ks][bs] = __builtin_amdgcn_mfma_f32_16x16x32_bf16(
                    AfC[ks], Bf[bs], acc[ks][bs], 0, 0, 0);

        if (s < 16) {
#pragma unroll
            for (int q = 0; q < 4; ++q) bdw[q] = cvtpk(bv[2 * q], bv[2 * q + 1]);
#pragma unroll
            for (int ks = 0; ks < 4; ++ks) AfC[ks] = AfN[ks];
        }
    }

#pragma unroll
    for (int ks = 0; ks < 4; ++ks)
#pragma unroll
        for (int bs = 0; bs < 4; ++bs) {
            int b = bs * 16 + r;
#pragma unroll
            for (int i = 0; i < 4; ++i) {
                int j = jblk + w * 64 + ks * 16 + g * 4 + i;
                out[(size_t)b * NPIX_ + start + j] = acc[ks][bs][i];
            }
        }
}

// ---------------------------------------------------------------------------
// K2b: cap synthesis (rings 0..126 and 384..510) — round-5 synth5 verbatim,
// restricted grid (off is always 0.5 on caps).
// ---------------------------------------------------------------------------
__global__ __launch_bounds__(256, 3) void synth_caps_k(
    const float* __restrict__ X,
    float* __restrict__ out)
{
    __shared__ __align__(16) unsigned int Adw[2][256 * 18];
    __shared__ __align__(16) unsigned int Bdw[2][64 * 18];

    int cid = blockIdx.x;
    int k  = (cid < 127) ? cid : (cid + 257);
    int jh = blockIdx.y;

    int nphi, start;
    if (k < NSIDE_ - 1) {
        nphi  = 4 * (k + 1);
        start = 2 * k * (k + 1);
    } else {
        int t = NLAT_ - k;
        nphi  = 4 * t;
        start = NPIX_ - 2 * t * (t + 1);
    }
    int jblk = jh * 256;
    if (jblk >= nphi) return;

    int tid  = threadIdx.x;
    int lane = tid & 63, w = tid >> 6;
    int r = lane & 15, g = lane >> 4;

    float theta = TWO_PI_ * ((float)(jblk + tid) + 0.5f) / (float)nphi;
    float dc, ds;
    sincosf(theta, &ds, &dc);
    float cs = 1.f, sn = 0.f;

    int bb = tid & 63, kq = tid >> 6;
    const float* Xk = X + (size_t)k * (MMAX_ * 128) + bb;

    int swzA = ((tid >> 4) & 3) << 2;
    int swzB = ((bb  >> 4) & 3) << 2;

    float bv[8];
#pragma unroll
    for (int i = 0; i < 8; ++i) {
        int kap = kq * 8 + i;
        bv[i] = Xk[(size_t)(kap >> 1) * 128 + (kap & 1) * 64];
    }
    unsigned int adw[16];
#pragma unroll
    for (int mi2 = 0; mi2 < 16; ++mi2) {
        adw[mi2] = cvtpk(cs, -sn);
        float cn = fmaf(cs, dc, -(sn * ds));
        float s2 = fmaf(sn, dc,  cs * ds);
        cs = cn; sn = s2;
    }
    unsigned int bdw[4];
#pragma unroll
    for (int q = 0; q < 4; ++q) bdw[q] = cvtpk(bv[2 * q], bv[2 * q + 1]);

    bool wact = (jblk + w * 64) < nphi;

    f32x4 acc[4][4];
#pragma unroll
    for (int a = 0; a < 4; ++a)
#pragma unroll
        for (int c = 0; c < 4; ++c) acc[a][c] = (f32x4){0.f, 0.f, 0.f, 0.f};

#pragma unroll 2
    for (int s = 0; s < 17; ++s) {
        const int bsel = s & 1;
        {
            unsigned int* ap = &Adw[bsel][tid * 18];
#pragma unroll
            for (int q = 0; q < 8; ++q)
                *(uint2*)(ap + ((2 * q) ^ swzA)) = make_uint2(adw[2 * q], adw[2 * q + 1]);
            unsigned int* bp = &Bdw[bsel][bb * 18];
            int cb = (kq * 4) ^ swzB;
            *(uint2*)(bp + cb)     = make_uint2(bdw[0], bdw[1]);
            *(uint2*)(bp + cb + 2) = make_uint2(bdw[2], bdw[3]);
        }
        __syncthreads();

        if (s < 16) {
            int kap0 = (s + 1) * 32 + kq * 8;
#pragma unroll
            for (int i = 0; i < 8; ++i) {
                int kap = kap0 + i;
                int mm  = kap >> 1;
                bv[i] = (mm < MMAX_) ? Xk[(size_t)mm * 128 + (kap & 1) * 64] : 0.f;
            }
#pragma unroll
            for (int mi2 = 0; mi2 < 16; ++mi2) {
                adw[mi2] = cvtpk(cs, -sn);
                float cn = fmaf(cs, dc, -(sn * ds));
                float s2 = fmaf(sn, dc,  cs * ds);
                cs = cn; sn = s2;
            }
        }

        if (wact) {
            const unsigned int* arp = &Adw[bsel][0];
            const unsigned int* brp = &Bdw[bsel][0];
            bf16x8 Af[4], Bf[4];
#pragma unroll
            for (int ks = 0; ks < 4; ++ks) {
                int row = w * 64 + ks * 16 + r;
                Af[ks] = ld_pair(arp + row * 18 + ((g * 4) ^ ((ks & 3) << 2)));
            }
#pragma unroll
            for (int bs = 0; bs < 4; ++bs) {
                int row = bs * 16 + r;
                Bf[bs] = ld_pair(brp + row * 18 + ((g * 4) ^ ((bs & 3) << 2)));
            }
#pragma unroll
            for (int ks = 0; ks < 4; ++ks)
#pragma unroll
                for (int bs = 0; bs < 4; ++bs)
                    acc[ks][bs] = __builtin_amdgcn_mfma_f32_16x16x32_bf16(
                        Af[ks], Bf[bs], acc[ks][bs], 0, 0, 0);
        }

        if (s < 16) {
#pragma unroll
            for (int q = 0; q < 4; ++q) bdw[q] = cvtpk(bv[2 * q], bv[2 * q + 1]);
        }
    }

    if (wact) {
#pragma unroll
        for (int ks = 0; ks < 4; ++ks)
#pragma unroll
            for (int bs = 0; bs < 4; ++bs) {
                int b = bs * 16 + r;
#pragma unroll
                for (int i = 0; i < 4; ++i) {
                    int j = jblk + w * 64 + ks * 16 + g * 4 + i;
                    if (j < nphi)
                        out[(size_t)b * NPIX_ + start + j] = acc[ks][bs][i];
                }
            }
    }
}

// ---------------------------------------------------------------------------
// Fallbacks (small ws): round-2 proven kernels.
// ---------------------------------------------------------------------------
__global__ __launch_bounds__(256) void legendre_k(
    const float* __restrict__ x,
    const float* __restrict__ pct,
    float* __restrict__ X)
{
    int k  = blockIdx.x * 256 + threadIdx.x;
    int m  = blockIdx.y;
    int bh = blockIdx.z;
    bool active = (k < NLAT_);
    if (!active) k = NLAT_ - 1;

    float accR[32], accI[32];
#pragma unroll
    for (int i = 0; i < 32; ++i) { accR[i] = 0.f; accI[i] = 0.f; }

    const float* pcol  = pct + (size_t)m * LMAX_ * NLAT_ + k;
    const float* xbase = x + (size_t)(bh * 32) * LMAX_ * MMAX_ * 2 + (size_t)m * 2;
    const size_t bstride = (size_t)LMAX_ * MMAX_ * 2;

    for (int l = 0; l < LMAX_; ++l) {
        float p = pcol[(size_t)l * NLAT_];
        const float* xl = xbase + (size_t)l * MMAX_ * 2;
#pragma unroll
        for (int bb = 0; bb < 32; ++bb) {
            accR[bb] = fmaf(xl[(size_t)bb * bstride],     p, accR[bb]);
            accI[bb] = fmaf(xl[(size_t)bb * bstride + 1], p, accI[bb]);
        }
    }
    if (active) {
        float wv = (m == 0) ? 1.f : 2.f;
        size_t base = ((size_t)k * MMAX_ + m) * 128 + bh * 32;
#pragma unroll
        for (int bb = 0; bb < 32; ++bb) {
            X[base + bb]      = accR[bb] * wv;
            X[base + 64 + bb] = accI[bb] * wv;
        }
    }
}

__global__ __launch_bounds__(256) void synth2_k(
    const float* __restrict__ X,
    float* __restrict__ out)
{
    int k  = blockIdx.x;
    int j  = blockIdx.y * 256 + threadIdx.x;
    int bh = blockIdx.z;

    int nphi, start; float off;
    if (k < NSIDE_ - 1) {
        nphi  = 4 * (k + 1);
        start = 2 * k * (k + 1);
        off   = 0.5f;
    } else if (k <= 3 * NSIDE_ - 1) {
        nphi  = 4 * NSIDE_;
        start = 2 * (NSIDE_ - 1) * NSIDE_ + (k - (NSIDE_ - 1)) * 4 * NSIDE_;
        off   = (((k - (NSIDE_ - 1)) & 1) == 0) ? 0.5f : 0.f;
    } else {
        int t = NLAT_ - k;
        nphi  = 4 * t;
        start = NPIX_ - 2 * t * (t + 1);
        off   = 0.5f;
    }
    if (blockIdx.y == 1 && nphi <= 256) return;
    bool store_ok = (j < nphi);

    float ang = TWO_PI_ * ((float)j + off) / (float)nphi;
    float dsn, dcs;
    sincosf(ang, &dsn, &dcs);

    const float* Xk = X + (size_t)k * MMAX_ * 128 + bh * 32;

    float acc[32];
#pragma unroll
    for (int i = 0; i < 32; ++i) acc[i] = 0.f;

    float c = 1.f, s = 0.f;
    for (int m = 0; m < MMAX_; ++m) {
        const float* xm = Xk + (size_t)m * 128;
#pragma unroll
        for (int bb = 0; bb < 32; ++bb) {
            acc[bb] = fmaf(c, xm[bb], acc[bb]);
            acc[bb] = fmaf(-s, xm[64 + bb], acc[bb]);
        }
        float cn = fmaf(c, dcs, -(s * dsn));
        float s2 = fmaf(s, dcs,  (c * dsn));
        c = cn; s = s2;
    }

    if (store_ok) {
        float* op = out + (size_t)(bh * 32) * NPIX_ + start + j;
#pragma unroll
        for (int bb = 0; bb < 32; ++bb)
            op[(size_t)bb * NPIX_] = acc[bb];
    }
}

// ---------------------------------------------------------------------------
extern "C" void kernel_launch(void* const* d_in, const int* in_sizes, int n_in,
                              void* d_out, int out_size, void* d_ws, size_t ws_size,
                              hipStream_t stream)
{
    const float* x   = (const float*)d_in[0];
    const float* pct = (const float*)d_in[1];
    // d_in[2]=A, d_in[3]=B, d_in[4]=fidx unused (trig + ring offsets on device)
    float* out = (float*)d_out;
    float* X   = (float*)d_ws;                                  // 67.24 MB

    size_t need = (size_t)XELEMS_ * 4 + (size_t)X2TELEMS_ * 2 + (size_t)TELEMS_ * 2;
    if (ws_size >= need) {
        unsigned short* x2T = (unsigned short*)(X + XELEMS_);
        unsigned short* T   = x2T + X2TELEMS_;
        trig_k<<<dim3(4), dim3(256), 0, stream>>>(T);
        pack_x_k<<<dim3(64, 16), dim3(256), 0, stream>>>(x, x2T);
        legendre5_k<<<dim3(1056), dim3(256), 0, stream>>>(x2T, pct, X);
        synth_belt_k<<<dim3(257, 2), dim3(256), 0, stream>>>(X, T, out);
        synth_caps_k<<<dim3(254, 2), dim3(256), 0, stream>>>(X, out);
    } else {
        legendre_k<<<dim3(2, MMAX_, 2), dim3(256), 0, stream>>>(x, pct, X);
        synth2_k<<<dim3(NLAT_, 2, 2), dim3(256), 0, stream>>>(X, out);
    }
}

// Round 9
// 235.992 us; speedup vs baseline: 1.1260x; 1.1260x over previous
//
#include <hip/hip_runtime.h>
#include <cstddef>

#define NSIDE_ 128
#define NLAT_  511
#define NLON_  512
#define LMAX_  511
#define MMAX_  257
#define NPIX_  196608
#define TWO_PI_ 6.28318530717958647692f

#define XELEMS_   16809856u   // 511*257*128 floats (X, f32, [k][m][rb])
#define X2TELEMS_ 16842752u   // 257*128*512 ushorts (x2T bf16, [m][rb][l])

typedef __attribute__((ext_vector_type(8))) short bf16x8;
typedef __attribute__((ext_vector_type(4))) float f32x4;

static __device__ __forceinline__ unsigned short f2bf(float f) {
    union { float f; unsigned int u; } v; v.f = f;
    unsigned int r = v.u + 0x7FFFu + ((v.u >> 16) & 1u);   // RNE
    return (unsigned short)(r >> 16);
}

static __device__ __forceinline__ unsigned int cvtpk(float lo, float hi) {
    unsigned int d;
    asm("v_cvt_pk_bf16_f32 %0, %1, %2" : "=v"(d) : "v"(lo), "v"(hi));
    return d;
}

static __device__ __forceinline__ bf16x8 ld_pair(const unsigned int* p) {
    union { struct { uint2 a, b; } s; bf16x8 v; } t;
    t.s.a = *(const uint2*)p;
    t.s.b = *(const uint2*)(p + 2);
    return t.v;
}

// ---------------------------------------------------------------------------
// K0: pack x[b][l][m][ri] (f32) -> x2T[m][rb][l] (bf16), rb = ri*64+b,
// l zero-padded to 512.  (round-5 verbatim)
// ---------------------------------------------------------------------------
__global__ __launch_bounds__(256) void pack_x_k(
    const float* __restrict__ x, unsigned short* __restrict__ x2T)
{
    __shared__ unsigned short lds[32][520];
    int b   = blockIdx.x;
    int l0  = blockIdx.y * 32;
    int tid = threadIdx.x;

    const float* src = x + ((size_t)b * LMAX_ + l0) * (2 * MMAX_);
    for (int li = 0; li < 32; ++li) {
        bool valid = (l0 + li) < LMAX_;
        for (int m2 = tid; m2 < 2 * MMAX_; m2 += 256) {
            float f = valid ? src[(size_t)li * (2 * MMAX_) + m2] : 0.f;
            lds[li][m2] = f2bf(f);
        }
    }
    __syncthreads();

    for (int m2 = tid; m2 < 2 * MMAX_; m2 += 256) {
        int m  = m2 >> 1;
        int rb = (m2 & 1) * 64 + b;
        unsigned short* dst = x2T + ((size_t)m * 128 + rb) * 512 + l0;
#pragma unroll
        for (int g = 0; g < 4; ++g) {
            unsigned int w0 = (unsigned int)lds[g*8+0][m2] | ((unsigned int)lds[g*8+1][m2] << 16);
            unsigned int w1 = (unsigned int)lds[g*8+2][m2] | ((unsigned int)lds[g*8+3][m2] << 16);
            unsigned int w2 = (unsigned int)lds[g*8+4][m2] | ((unsigned int)lds[g*8+5][m2] << 16);
            unsigned int w3 = (unsigned int)lds[g*8+6][m2] | ((unsigned int)lds[g*8+7][m2] << 16);
            *(uint4*)(dst + g * 8) = make_uint4(w0, w1, w2, w3);
        }
    }
}

// ---------------------------------------------------------------------------
// K1: Legendre MFMA, k-tile 64 (2x the blocks of r5 -> 8.25 blocks/CU),
// 4 blocks/CU resident via __launch_bounds__(256,4).
//   C[k][rb] = sum_l pct[m][l][k] * x2T[m][rb][l]
// Per block: 64k x 128rb, 16 K-steps of 32; waves 2x2 of 32k x 64rb
// (acc[2][4] = 32 VGPR). Same LDS swizzle/pipeline structure as round 5.
// ---------------------------------------------------------------------------
__global__ __launch_bounds__(256, 4) void legendre9_k(
    const unsigned short* __restrict__ x2T,
    const float* __restrict__ pct,
    float* __restrict__ X)
{
    __shared__ __align__(16) unsigned int Apk[2][64 * 18];   // 2 x 4608 B

    int bid = blockIdx.x;
    int xcd = bid & 7, n = bid >> 3;
    int kt = n & 7, mi = n >> 3;
    int m = mi * 8 + xcd;                 // same-m blocks land on one XCD
    if (m >= MMAX_) return;

    int k0  = kt * 64;
    int tid = threadIdx.x;
    int lane = tid & 63, w = tid >> 6;
    int wk = (w >> 1) * 32, wrb = (w & 1) * 64;
    int r = lane & 15, g = lane >> 4;

    const float* pctm = pct + (size_t)m * (LMAX_ * NLAT_);
    const unsigned short* x2m = x2T + (size_t)m * (128 * 512);

    int kc = tid & 15;                    // k column within tile (16 of 64)
    int lp = tid >> 4;                    // l-pair 0..15
    // i=3 clamp: only kt=7,kc=15 hits k=511 -> reuse k=510 (store-masked)
    int o3 = (k0 + kc + 48 <= NLAT_ - 1) ? 48 : (NLAT_ - 1 - (k0 + kc));

    f32x4 acc[2][4];
#pragma unroll
    for (int a = 0; a < 2; ++a)
#pragma unroll
        for (int c = 0; c < 4; ++c) acc[a][c] = (f32x4){0.f, 0.f, 0.f, 0.f};

    float e0[4], e1[4];
    bf16x8 Bfc[4], Bfn[4];

    auto load_pct = [&](int step) {
        int la = step * 32 + 2 * lp, lb = la + 1;
        if (lb > LMAX_ - 1) lb = LMAX_ - 1;            // l=511 pad (B zero)
        const float* pa = pctm + (size_t)la * NLAT_ + k0 + kc;
        const float* pb = pctm + (size_t)lb * NLAT_ + k0 + kc;
#pragma unroll
        for (int i = 0; i < 3; ++i) { e0[i] = pa[16 * i]; e1[i] = pb[16 * i]; }
        e0[3] = pa[o3]; e1[3] = pb[o3];
    };
    auto load_B = [&](int step, bf16x8* dst) {
        int lbase = step * 32 + g * 8;
#pragma unroll
        for (int rs = 0; rs < 4; ++rs)
            dst[rs] = *(const bf16x8*)(x2m + (size_t)(wrb + rs * 16 + r) * 512 + lbase);
    };

    // prologue
    load_pct(0);
    load_B(0, Bfc);

#pragma unroll 2
    for (int s = 0; s < 16; ++s) {
        const int bsel = s & 1;
        unsigned int* wp = &Apk[bsel][0];
#pragma unroll
        for (int i = 0; i < 4; ++i) {
            unsigned int dwv = cvtpk(e0[i], e1[i]);    // (l even, l odd)
            int kk = kc + 16 * i;
            wp[kk * 18 + (lp ^ ((i & 3) << 2))] = dwv;
        }
        __syncthreads();

        if (s < 15) { load_pct(s + 1); load_B(s + 1, Bfn); }

        const unsigned int* rp = &Apk[bsel][0];
        bf16x8 Af[2];
#pragma unroll
        for (int ks = 0; ks < 2; ++ks) {
            int row = wk + ks * 16 + r;
            Af[ks] = ld_pair(rp + row * 18 + ((g * 4) ^ (((row >> 4) & 3) << 2)));
        }
#pragma unroll
        for (int ks = 0; ks < 2; ++ks)
#pragma unroll
            for (int rs = 0; rs < 4; ++rs)
                acc[ks][rs] = __builtin_amdgcn_mfma_f32_16x16x32_bf16(
                    Af[ks], Bfc[rs], acc[ks][rs], 0, 0, 0);

        if (s < 15) {
#pragma unroll
            for (int rs = 0; rs < 4; ++rs) Bfc[rs] = Bfn[rs];
        }
    }

    float wgt = (m == 0) ? 1.f : 2.f;
#pragma unroll
    for (int ks = 0; ks < 2; ++ks) {
#pragma unroll
        for (int rs = 0; rs < 4; ++rs) {
            int rb = wrb + rs * 16 + r;
#pragma unroll
            for (int i = 0; i < 4; ++i) {
                int k = k0 + wk + ks * 16 + g * 4 + i;
                if (k < NLAT_)
                    X[((size_t)k * MMAX_ + m) * 128 + rb] = acc[ks][rs][i] * wgt;
            }
        }
    }
}

// ---------------------------------------------------------------------------
// K2: synthesis MFMA (round-5 verbatim: 1 barrier/step, dbuf, prefetch,
// trig recurrence on VALU overlapping MFMA).
// ---------------------------------------------------------------------------
__global__ __launch_bounds__(256, 3) void synth5_k(
    const float* __restrict__ X,
    float* __restrict__ out)
{
    __shared__ __align__(16) unsigned int Adw[2][256 * 18];
    __shared__ __align__(16) unsigned int Bdw[2][64 * 18];

    int k  = blockIdx.x;
    int jh = blockIdx.y;

    int nphi, start; float off;
    if (k < NSIDE_ - 1) {
        nphi  = 4 * (k + 1);
        start = 2 * k * (k + 1);
        off   = 0.5f;
    } else if (k <= 3 * NSIDE_ - 1) {
        nphi  = 4 * NSIDE_;
        start = 2 * (NSIDE_ - 1) * NSIDE_ + (k - (NSIDE_ - 1)) * 4 * NSIDE_;
        off   = (((k - (NSIDE_ - 1)) & 1) == 0) ? 0.5f : 0.f;
    } else {
        int t = NLAT_ - k;
        nphi  = 4 * t;
        start = NPIX_ - 2 * t * (t + 1);
        off   = 0.5f;
    }
    int jblk = jh * 256;
    if (jblk >= nphi) return;

    int tid  = threadIdx.x;
    int lane = tid & 63, w = tid >> 6;
    int r = lane & 15, g = lane >> 4;

    float theta = TWO_PI_ * ((float)(jblk + tid) + off) / (float)nphi;
    float dc, ds;
    sincosf(theta, &ds, &dc);
    float cs = 1.f, sn = 0.f;

    int bb = tid & 63, kq = tid >> 6;
    const float* Xk = X + (size_t)k * (MMAX_ * 128) + bb;

    int swzA = ((tid >> 4) & 3) << 2;
    int swzB = ((bb  >> 4) & 3) << 2;

    float bv[8];
#pragma unroll
    for (int i = 0; i < 8; ++i) {
        int kap = kq * 8 + i;
        bv[i] = Xk[(size_t)(kap >> 1) * 128 + (kap & 1) * 64];
    }
    unsigned int adw[16];
#pragma unroll
    for (int mi2 = 0; mi2 < 16; ++mi2) {
        adw[mi2] = cvtpk(cs, -sn);
        float cn = fmaf(cs, dc, -(sn * ds));
        float s2 = fmaf(sn, dc,  cs * ds);
        cs = cn; sn = s2;
    }
    unsigned int bdw[4];
#pragma unroll
    for (int q = 0; q < 4; ++q) bdw[q] = cvtpk(bv[2 * q], bv[2 * q + 1]);

    bool wact = (jblk + w * 64) < nphi;

    f32x4 acc[4][4];
#pragma unroll
    for (int a = 0; a < 4; ++a)
#pragma unroll
        for (int c = 0; c < 4; ++c) acc[a][c] = (f32x4){0.f, 0.f, 0.f, 0.f};

#pragma unroll 2
    for (int s = 0; s < 17; ++s) {
        const int bsel = s & 1;
        {
            unsigned int* ap = &Adw[bsel][tid * 18];
#pragma unroll
            for (int q = 0; q < 8; ++q)
                *(uint2*)(ap + ((2 * q) ^ swzA)) = make_uint2(adw[2 * q], adw[2 * q + 1]);
            unsigned int* bp = &Bdw[bsel][bb * 18];
            int cb = (kq * 4) ^ swzB;
            *(uint2*)(bp + cb)     = make_uint2(bdw[0], bdw[1]);
            *(uint2*)(bp + cb + 2) = make_uint2(bdw[2], bdw[3]);
        }
        __syncthreads();

        if (s < 16) {
            int kap0 = (s + 1) * 32 + kq * 8;
#pragma unroll
            for (int i = 0; i < 8; ++i) {
                int kap = kap0 + i;
                int mm  = kap >> 1;
                bv[i] = (mm < MMAX_) ? Xk[(size_t)mm * 128 + (kap & 1) * 64] : 0.f;
            }
        }
        if (s < 16) {
#pragma unroll
            for (int mi2 = 0; mi2 < 16; ++mi2) {
                adw[mi2] = cvtpk(cs, -sn);
                float cn = fmaf(cs, dc, -(sn * ds));
                float s2 = fmaf(sn, dc,  cs * ds);
                cs = cn; sn = s2;
            }
        }

        if (wact) {
            const unsigned int* arp = &Adw[bsel][0];
            const unsigned int* brp = &Bdw[bsel][0];
            bf16x8 Af[4], Bf[4];
#pragma unroll
            for (int ks = 0; ks < 4; ++ks) {
                int row = w * 64 + ks * 16 + r;
                Af[ks] = ld_pair(arp + row * 18 + ((g * 4) ^ ((ks & 3) << 2)));
            }
#pragma unroll
            for (int bs = 0; bs < 4; ++bs) {
                int row = bs * 16 + r;
                Bf[bs] = ld_pair(brp + row * 18 + ((g * 4) ^ ((bs & 3) << 2)));
            }
#pragma unroll
            for (int ks = 0; ks < 4; ++ks)
#pragma unroll
                for (int bs = 0; bs < 4; ++bs)
                    acc[ks][bs] = __builtin_amdgcn_mfma_f32_16x16x32_bf16(
                        Af[ks], Bf[bs], acc[ks][bs], 0, 0, 0);
        }

        if (s < 16) {
#pragma unroll
            for (int q = 0; q < 4; ++q) bdw[q] = cvtpk(bv[2 * q], bv[2 * q + 1]);
        }
    }

    if (wact) {
#pragma unroll
        for (int ks = 0; ks < 4; ++ks)
#pragma unroll
            for (int bs = 0; bs < 4; ++bs) {
                int b = bs * 16 + r;
#pragma unroll
                for (int i = 0; i < 4; ++i) {
                    int j = jblk + w * 64 + ks * 16 + g * 4 + i;
                    if (j < nphi)
                        out[(size_t)b * NPIX_ + start + j] = acc[ks][bs][i];
                }
            }
    }
}

// ---------------------------------------------------------------------------
// Fallbacks (small ws): round-2 proven kernels.
// ---------------------------------------------------------------------------
__global__ __launch_bounds__(256) void legendre_k(
    const float* __restrict__ x,
    const float* __restrict__ pct,
    float* __restrict__ X)
{
    int k  = blockIdx.x * 256 + threadIdx.x;
    int m  = blockIdx.y;
    int bh = blockIdx.z;
    bool active = (k < NLAT_);
    if (!active) k = NLAT_ - 1;

    float accR[32], accI[32];
#pragma unroll
    for (int i = 0; i < 32; ++i) { accR[i] = 0.f; accI[i] = 0.f; }

    const float* pcol  = pct + (size_t)m * LMAX_ * NLAT_ + k;
    const float* xbase = x + (size_t)(bh * 32) * LMAX_ * MMAX_ * 2 + (size_t)m * 2;
    const size_t bstride = (size_t)LMAX_ * MMAX_ * 2;

    for (int l = 0; l < LMAX_; ++l) {
        float p = pcol[(size_t)l * NLAT_];
        const float* xl = xbase + (size_t)l * MMAX_ * 2;
#pragma unroll
        for (int bb = 0; bb < 32; ++bb) {
            accR[bb] = fmaf(xl[(size_t)bb * bstride],     p, accR[bb]);
            accI[bb] = fmaf(xl[(size_t)bb * bstride + 1], p, accI[bb]);
        }
    }
    if (active) {
        float wv = (m == 0) ? 1.f : 2.f;
        size_t base = ((size_t)k * MMAX_ + m) * 128 + bh * 32;
#pragma unroll
        for (int bb = 0; bb < 32; ++bb) {
            X[base + bb]      = accR[bb] * wv;
            X[base + 64 + bb] = accI[bb] * wv;
        }
    }
}

__global__ __launch_bounds__(256) void synth2_k(
    const float* __restrict__ X,
    float* __restrict__ out)
{
    int k  = blockIdx.x;
    int j  = blockIdx.y * 256 + threadIdx.x;
    int bh = blockIdx.z;

    int nphi, start; float off;
    if (k < NSIDE_ - 1) {
        nphi  = 4 * (k + 1);
        start = 2 * k * (k + 1);
        off   = 0.5f;
    } else if (k <= 3 * NSIDE_ - 1) {
        nphi  = 4 * NSIDE_;
        start = 2 * (NSIDE_ - 1) * NSIDE_ + (k - (NSIDE_ - 1)) * 4 * NSIDE_;
        off   = (((k - (NSIDE_ - 1)) & 1) == 0) ? 0.5f : 0.f;
    } else {
        int t = NLAT_ - k;
        nphi  = 4 * t;
        start = NPIX_ - 2 * t * (t + 1);
        off   = 0.5f;
    }
    if (blockIdx.y == 1 && nphi <= 256) return;
    bool store_ok = (j < nphi);

    float ang = TWO_PI_ * ((float)j + off) / (float)nphi;
    float dsn, dcs;
    sincosf(ang, &dsn, &dcs);

    const float* Xk = X + (size_t)k * MMAX_ * 128 + bh * 32;

    float acc[32];
#pragma unroll
    for (int i = 0; i < 32; ++i) acc[i] = 0.f;

    float c = 1.f, s = 0.f;
    for (int m = 0; m < MMAX_; ++m) {
        const float* xm = Xk + (size_t)m * 128;
#pragma unroll
        for (int bb = 0; bb < 32; ++bb) {
            acc[bb] = fmaf(c, xm[bb], acc[bb]);
            acc[bb] = fmaf(-s, xm[64 + bb], acc[bb]);
        }
        float cn = fmaf(c, dcs, -(s * dsn));
        float s2 = fmaf(s, dcs,  (c * dsn));
        c = cn; s = s2;
    }

    if (store_ok) {
        float* op = out + (size_t)(bh * 32) * NPIX_ + start + j;
#pragma unroll
        for (int bb = 0; bb < 32; ++bb)
            op[(size_t)bb * NPIX_] = acc[bb];
    }
}

// ---------------------------------------------------------------------------
extern "C" void kernel_launch(void* const* d_in, const int* in_sizes, int n_in,
                              void* d_out, int out_size, void* d_ws, size_t ws_size,
                              hipStream_t stream)
{
    const float* x   = (const float*)d_in[0];
    const float* pct = (const float*)d_in[1];
    // d_in[2]=A, d_in[3]=B, d_in[4]=fidx unused (trig + ring offsets on device)
    float* out = (float*)d_out;
    float* X   = (float*)d_ws;                                  // 67.24 MB

    size_t need = (size_t)XELEMS_ * 4 + (size_t)X2TELEMS_ * 2;  // 100.9 MB
    if (ws_size >= need) {
        unsigned short* x2T = (unsigned short*)(X + XELEMS_);
        pack_x_k<<<dim3(64, 16), dim3(256), 0, stream>>>(x, x2T);
        legendre9_k<<<dim3(2112), dim3(256), 0, stream>>>(x2T, pct, X);
        synth5_k<<<dim3(NLAT_, 2), dim3(256), 0, stream>>>(X, out);
    } else {
        legendre_k<<<dim3(2, MMAX_, 2), dim3(256), 0, stream>>>(x, pct, X);
        synth2_k<<<dim3(NLAT_, 2, 2), dim3(256), 0, stream>>>(X, out);
    }
}

// Round 11
// 213.246 us; speedup vs baseline: 1.2461x; 1.1067x over previous
//
#include <hip/hip_runtime.h>
#include <cstddef>

#define NSIDE_ 128
#define NLAT_  511
#define NLON_  512
#define LMAX_  511
#define MMAX_  257
#define NPIX_  196608
#define TWO_PI_ 6.28318530717958647692f

#define XELEMS_   16809856u   // fallback: 511*257*128 floats (X f32)
#define X2ELEMS_  16809856u   // main: 511*257*2*64 ushorts (X bf16, [k][m][ri][b])
#define X2TELEMS_ 16842752u   // 257*128*512 ushorts (x2T bf16, [m][rb][l])

typedef __attribute__((ext_vector_type(8))) short bf16x8;
typedef __attribute__((ext_vector_type(4))) float f32x4;

static __device__ __forceinline__ unsigned short f2bf(float f) {
    union { float f; unsigned int u; } v; v.f = f;
    unsigned int r = v.u + 0x7FFFu + ((v.u >> 16) & 1u);   // RNE
    return (unsigned short)(r >> 16);
}

static __device__ __forceinline__ unsigned int cvtpk(float lo, float hi) {
    unsigned int d;
    asm("v_cvt_pk_bf16_f32 %0, %1, %2" : "=v"(d) : "v"(lo), "v"(hi));
    return d;
}

static __device__ __forceinline__ bf16x8 ld_pair(const unsigned int* p) {
    union { struct { uint2 a, b; } s; bf16x8 v; } t;
    t.s.a = *(const uint2*)p;
    t.s.b = *(const uint2*)(p + 2);
    return t.v;
}

// ---------------------------------------------------------------------------
// K0: pack x[b][l][m][ri] (f32) -> x2T[m][rb][l] (bf16), rb = ri*64+b,
// l zero-padded to 512.  (round-5 verbatim)
// ---------------------------------------------------------------------------
__global__ __launch_bounds__(256) void pack_x_k(
    const float* __restrict__ x, unsigned short* __restrict__ x2T)
{
    __shared__ unsigned short lds[32][520];
    int b   = blockIdx.x;
    int l0  = blockIdx.y * 32;
    int tid = threadIdx.x;

    const float* src = x + ((size_t)b * LMAX_ + l0) * (2 * MMAX_);
    for (int li = 0; li < 32; ++li) {
        bool valid = (l0 + li) < LMAX_;
        for (int m2 = tid; m2 < 2 * MMAX_; m2 += 256) {
            float f = valid ? src[(size_t)li * (2 * MMAX_) + m2] : 0.f;
            lds[li][m2] = f2bf(f);
        }
    }
    __syncthreads();

    for (int m2 = tid; m2 < 2 * MMAX_; m2 += 256) {
        int m  = m2 >> 1;
        int rb = (m2 & 1) * 64 + b;
        unsigned short* dst = x2T + ((size_t)m * 128 + rb) * 512 + l0;
#pragma unroll
        for (int g = 0; g < 4; ++g) {
            unsigned int w0 = (unsigned int)lds[g*8+0][m2] | ((unsigned int)lds[g*8+1][m2] << 16);
            unsigned int w1 = (unsigned int)lds[g*8+2][m2] | ((unsigned int)lds[g*8+3][m2] << 16);
            unsigned int w2 = (unsigned int)lds[g*8+4][m2] | ((unsigned int)lds[g*8+5][m2] << 16);
            unsigned int w3 = (unsigned int)lds[g*8+6][m2] | ((unsigned int)lds[g*8+7][m2] << 16);
            *(uint4*)(dst + g * 8) = make_uint4(w0, w1, w2, w3);
        }
    }
}

// ---------------------------------------------------------------------------
// K1: Legendre MFMA (round-5 structure, unchanged pipeline). Only delta:
// epilogue stores X as bf16 [k][m][ri][b] (lossless vs r5: the f32 X was
// only ever consumed through the same RNE bf16 conversion in synth).
// ---------------------------------------------------------------------------
__global__ __launch_bounds__(256, 3) void legendre5_k(
    const unsigned short* __restrict__ x2T,
    const float* __restrict__ pct,
    unsigned short* __restrict__ X2)
{
    __shared__ __align__(16) unsigned int Apk[2][128 * 18];

    int bid = blockIdx.x;
    int xcd = bid & 7, n = bid >> 3;
    int kt = n & 3, mi = n >> 2;
    int m = mi * 8 + xcd;
    if (m >= MMAX_) return;

    int k0  = kt * 128;
    int tid = threadIdx.x;
    int lane = tid & 63, w = tid >> 6;
    int wk = (w >> 1) * 64, wrb = (w & 1) * 64;
    int r = lane & 15, g = lane >> 4;

    const float* pctm = pct + (size_t)m * (LMAX_ * NLAT_);
    const unsigned short* x2m = x2T + (size_t)m * (128 * 512);

    int kc = tid & 15;
    int lp = tid >> 4;
    int o7 = (k0 + kc + 112 <= NLAT_ - 1) ? 112 : (NLAT_ - 1 - (k0 + kc));

    f32x4 acc[4][4];
#pragma unroll
    for (int a = 0; a < 4; ++a)
#pragma unroll
        for (int c = 0; c < 4; ++c) acc[a][c] = (f32x4){0.f, 0.f, 0.f, 0.f};

    float e0[8], e1[8];
    bf16x8 Bfc[4], Bfn[4];

    {
        const float* pa = pctm + (size_t)(2 * lp)     * NLAT_ + k0 + kc;
        const float* pb = pctm + (size_t)(2 * lp + 1) * NLAT_ + k0 + kc;
#pragma unroll
        for (int i = 0; i < 7; ++i) { e0[i] = pa[16 * i]; e1[i] = pb[16 * i]; }
        e0[7] = pa[o7]; e1[7] = pb[o7];
#pragma unroll
        for (int rs = 0; rs < 4; ++rs)
            Bfc[rs] = *(const bf16x8*)(x2m + (size_t)(wrb + rs * 16 + r) * 512 + g * 8);
    }

#pragma unroll 2
    for (int s = 0; s < 16; ++s) {
        const int bsel = s & 1;
        unsigned int* wp = &Apk[bsel][0];
#pragma unroll
        for (int i = 0; i < 8; ++i) {
            unsigned int dwv = cvtpk(e0[i], e1[i]);
            int kk = kc + 16 * i;
            wp[kk * 18 + (lp ^ ((i & 3) << 2))] = dwv;
        }
        __syncthreads();

        if (s < 15) {
            int l0n = (s + 1) * 32;
            int la = l0n + 2 * lp, lb = la + 1;
            if (lb > LMAX_ - 1) lb = LMAX_ - 1;
            const float* pa = pctm + (size_t)la * NLAT_ + k0 + kc;
            const float* pb = pctm + (size_t)lb * NLAT_ + k0 + kc;
#pragma unroll
            for (int i = 0; i < 7; ++i) { e0[i] = pa[16 * i]; e1[i] = pb[16 * i]; }
            e0[7] = pa[o7]; e1[7] = pb[o7];
            int lbase = l0n + g * 8;
#pragma unroll
            for (int rs = 0; rs < 4; ++rs)
                Bfn[rs] = *(const bf16x8*)(x2m + (size_t)(wrb + rs * 16 + r) * 512 + lbase);
        }

        const unsigned int* rp = &Apk[bsel][0];
        bf16x8 Af[4];
#pragma unroll
        for (int ks = 0; ks < 4; ++ks) {
            int row = wk + ks * 16 + r;
            Af[ks] = ld_pair(rp + row * 18 + ((g * 4) ^ ((ks & 3) << 2)));
        }
#pragma unroll
        for (int ks = 0; ks < 4; ++ks)
#pragma unroll
            for (int rs = 0; rs < 4; ++rs)
                acc[ks][rs] = __builtin_amdgcn_mfma_f32_16x16x32_bf16(
                    Af[ks], Bfc[rs], acc[ks][rs], 0, 0, 0);

        if (s < 15) {
#pragma unroll
            for (int rs = 0; rs < 4; ++rs) Bfc[rs] = Bfn[rs];
        }
    }

    float wgt = (m == 0) ? 1.f : 2.f;
#pragma unroll
    for (int ks = 0; ks < 4; ++ks) {
#pragma unroll
        for (int rs = 0; rs < 4; ++rs) {
            int rb = wrb + rs * 16 + r;
            int ri = rb >> 6, b = rb & 63;
#pragma unroll
            for (int i = 0; i < 4; ++i) {
                int k = k0 + wk + ks * 16 + g * 4 + i;
                if (k < NLAT_)
                    X2[(((size_t)k * MMAX_ + m) * 2 + ri) * 64 + b] =
                        f2bf(acc[ks][rs][i] * wgt);
            }
        }
    }
}

// ---------------------------------------------------------------------------
// K2: synthesis MFMA (round-5 structure, unchanged pipeline). Only delta:
// B-values load as bf16 ushorts from X2 (half the bytes), packed with
// or/shl instead of cvtpk — bit-identical MFMA inputs vs r5.
// ---------------------------------------------------------------------------
__global__ __launch_bounds__(256, 3) void synth5_k(
    const unsigned short* __restrict__ X2,
    float* __restrict__ out)
{
    __shared__ __align__(16) unsigned int Adw[2][256 * 18];
    __shared__ __align__(16) unsigned int Bdw[2][64 * 18];

    int k  = blockIdx.x;
    int jh = blockIdx.y;

    int nphi, start; float off;
    if (k < NSIDE_ - 1) {
        nphi  = 4 * (k + 1);
        start = 2 * k * (k + 1);
        off   = 0.5f;
    } else if (k <= 3 * NSIDE_ - 1) {
        nphi  = 4 * NSIDE_;
        start = 2 * (NSIDE_ - 1) * NSIDE_ + (k - (NSIDE_ - 1)) * 4 * NSIDE_;
        off   = (((k - (NSIDE_ - 1)) & 1) == 0) ? 0.5f : 0.f;
    } else {
        int t = NLAT_ - k;
        nphi  = 4 * t;
        start = NPIX_ - 2 * t * (t + 1);
        off   = 0.5f;
    }
    int jblk = jh * 256;
    if (jblk >= nphi) return;

    int tid  = threadIdx.x;
    int lane = tid & 63, w = tid >> 6;
    int r = lane & 15, g = lane >> 4;

    float theta = TWO_PI_ * ((float)(jblk + tid) + off) / (float)nphi;
    float dc, ds;
    sincosf(theta, &ds, &dc);
    float cs = 1.f, sn = 0.f;

    int bb = tid & 63, kq = tid >> 6;
    const unsigned short* Xk = X2 + (size_t)k * (MMAX_ * 2 * 64) + bb;

    int swzA = ((tid >> 4) & 3) << 2;
    int swzB = ((bb  >> 4) & 3) << 2;

    unsigned short hv[8];
#pragma unroll
    for (int i = 0; i < 8; ++i) {
        int kap = kq * 8 + i;
        hv[i] = Xk[((size_t)(kap >> 1) * 2 + (kap & 1)) * 64];
    }
    unsigned int adw[16];
#pragma unroll
    for (int mi2 = 0; mi2 < 16; ++mi2) {
        adw[mi2] = cvtpk(cs, -sn);
        float cn = fmaf(cs, dc, -(sn * ds));
        float s2 = fmaf(sn, dc,  cs * ds);
        cs = cn; sn = s2;
    }
    unsigned int bdw[4];
#pragma unroll
    for (int q = 0; q < 4; ++q)
        bdw[q] = (unsigned int)hv[2 * q] | ((unsigned int)hv[2 * q + 1] << 16);

    bool wact = (jblk + w * 64) < nphi;

    f32x4 acc[4][4];
#pragma unroll
    for (int a = 0; a < 4; ++a)
#pragma unroll
        for (int c = 0; c < 4; ++c) acc[a][c] = (f32x4){0.f, 0.f, 0.f, 0.f};

#pragma unroll 2
    for (int s = 0; s < 17; ++s) {
        const int bsel = s & 1;
        {
            unsigned int* ap = &Adw[bsel][tid * 18];
#pragma unroll
            for (int q = 0; q < 8; ++q)
                *(uint2*)(ap + ((2 * q) ^ swzA)) = make_uint2(adw[2 * q], adw[2 * q + 1]);
            unsigned int* bp = &Bdw[bsel][bb * 18];
            int cb = (kq * 4) ^ swzB;
            *(uint2*)(bp + cb)     = make_uint2(bdw[0], bdw[1]);
            *(uint2*)(bp + cb + 2) = make_uint2(bdw[2], bdw[3]);
        }
        __syncthreads();

        if (s < 16) {
            int kap0 = (s + 1) * 32 + kq * 8;
#pragma unroll
            for (int i = 0; i < 8; ++i) {
                int kap = kap0 + i;
                int mm  = kap >> 1;
                hv[i] = (mm < MMAX_) ? Xk[((size_t)mm * 2 + (kap & 1)) * 64]
                                     : (unsigned short)0;
            }
        }
        if (s < 16) {
#pragma unroll
            for (int mi2 = 0; mi2 < 16; ++mi2) {
                adw[mi2] = cvtpk(cs, -sn);
                float cn = fmaf(cs, dc, -(sn * ds));
                float s2 = fmaf(sn, dc,  cs * ds);
                cs = cn; sn = s2;
            }
        }

        if (wact) {
            const unsigned int* arp = &Adw[bsel][0];
            const unsigned int* brp = &Bdw[bsel][0];
            bf16x8 Af[4], Bf[4];
#pragma unroll
            for (int ks = 0; ks < 4; ++ks) {
                int row = w * 64 + ks * 16 + r;
                Af[ks] = ld_pair(arp + row * 18 + ((g * 4) ^ ((ks & 3) << 2)));
            }
#pragma unroll
            for (int bs = 0; bs < 4; ++bs) {
                int row = bs * 16 + r;
                Bf[bs] = ld_pair(brp + row * 18 + ((g * 4) ^ ((bs & 3) << 2)));
            }
#pragma unroll
            for (int ks = 0; ks < 4; ++ks)
#pragma unroll
                for (int bs = 0; bs < 4; ++bs)
                    acc[ks][bs] = __builtin_amdgcn_mfma_f32_16x16x32_bf16(
                        Af[ks], Bf[bs], acc[ks][bs], 0, 0, 0);
        }

        if (s < 16) {
#pragma unroll
            for (int q = 0; q < 4; ++q)
                bdw[q] = (unsigned int)hv[2 * q] | ((unsigned int)hv[2 * q + 1] << 16);
        }
    }

    if (wact) {
#pragma unroll
        for (int ks = 0; ks < 4; ++ks)
#pragma unroll
            for (int bs = 0; bs < 4; ++bs) {
                int b = bs * 16 + r;
#pragma unroll
                for (int i = 0; i < 4; ++i) {
                    int j = jblk + w * 64 + ks * 16 + g * 4 + i;
                    if (j < nphi)
                        out[(size_t)b * NPIX_ + start + j] = acc[ks][bs][i];
                }
            }
    }
}

// ---------------------------------------------------------------------------
// Fallbacks (small ws): round-2 proven kernels (f32 X in d_ws).
// ---------------------------------------------------------------------------
__global__ __launch_bounds__(256) void legendre_k(
    const float* __restrict__ x,
    const float* __restrict__ pct,
    float* __restrict__ X)
{
    int k  = blockIdx.x * 256 + threadIdx.x;
    int m  = blockIdx.y;
    int bh = blockIdx.z;
    bool active = (k < NLAT_);
    if (!active) k = NLAT_ - 1;

    float accR[32], accI[32];
#pragma unroll
    for (int i = 0; i < 32; ++i) { accR[i] = 0.f; accI[i] = 0.f; }

    const float* pcol  = pct + (size_t)m * LMAX_ * NLAT_ + k;
    const float* xbase = x + (size_t)(bh * 32) * LMAX_ * MMAX_ * 2 + (size_t)m * 2;
    const size_t bstride = (size_t)LMAX_ * MMAX_ * 2;

    for (int l = 0; l < LMAX_; ++l) {
        float p = pcol[(size_t)l * NLAT_];
        const float* xl = xbase + (size_t)l * MMAX_ * 2;
#pragma unroll
        for (int bb = 0; bb < 32; ++bb) {
            accR[bb] = fmaf(xl[(size_t)bb * bstride],     p, accR[bb]);
            accI[bb] = fmaf(xl[(size_t)bb * bstride + 1], p, accI[bb]);
        }
    }
    if (active) {
        float wv = (m == 0) ? 1.f : 2.f;
        size_t base = ((size_t)k * MMAX_ + m) * 128 + bh * 32;
#pragma unroll
        for (int bb = 0; bb < 32; ++bb) {
            X[base + bb]      = accR[bb] * wv;
            X[base + 64 + bb] = accI[bb] * wv;
        }
    }
}

__global__ __launch_bounds__(256) void synth2_k(
    const float* __restrict__ X,
    float* __restrict__ out)
{
    int k  = blockIdx.x;
    int j  = blockIdx.y * 256 + threadIdx.x;
    int bh = blockIdx.z;

    int nphi, start; float off;
    if (k < NSIDE_ - 1) {
        nphi  = 4 * (k + 1);
        start = 2 * k * (k + 1);
        off   = 0.5f;
    } else if (k <= 3 * NSIDE_ - 1) {
        nphi  = 4 * NSIDE_;
        start = 2 * (NSIDE_ - 1) * NSIDE_ + (k - (NSIDE_ - 1)) * 4 * NSIDE_;
        off   = (((k - (NSIDE_ - 1)) & 1) == 0) ? 0.5f : 0.f;
    } else {
        int t = NLAT_ - k;
        nphi  = 4 * t;
        start = NPIX_ - 2 * t * (t + 1);
        off   = 0.5f;
    }
    if (blockIdx.y == 1 && nphi <= 256) return;
    bool store_ok = (j < nphi);

    float ang = TWO_PI_ * ((float)j + off) / (float)nphi;
    float dsn, dcs;
    sincosf(ang, &dsn, &dcs);

    const float* Xk = X + (size_t)k * MMAX_ * 128 + bh * 32;

    float acc[32];
#pragma unroll
    for (int i = 0; i < 32; ++i) acc[i] = 0.f;

    float c = 1.f, s = 0.f;
    for (int m = 0; m < MMAX_; ++m) {
        const float* xm = Xk + (size_t)m * 128;
#pragma unroll
        for (int bb = 0; bb < 32; ++bb) {
            acc[bb] = fmaf(c, xm[bb], acc[bb]);
            acc[bb] = fmaf(-s, xm[64 + bb], acc[bb]);
        }
        float cn = fmaf(c, dcs, -(s * dsn));
        float s2 = fmaf(s, dcs,  (c * dsn));
        c = cn; s = s2;
    }

    if (store_ok) {
        float* op = out + (size_t)(bh * 32) * NPIX_ + start + j;
#pragma unroll
        for (int bb = 0; bb < 32; ++bb)
            op[(size_t)bb * NPIX_] = acc[bb];
    }
}

// ---------------------------------------------------------------------------
extern "C" void kernel_launch(void* const* d_in, const int* in_sizes, int n_in,
                              void* d_out, int out_size, void* d_ws, size_t ws_size,
                              hipStream_t stream)
{
    const float* x   = (const float*)d_in[0];
    const float* pct = (const float*)d_in[1];
    // d_in[2]=A, d_in[3]=B, d_in[4]=fidx unused (trig + ring offsets on device)
    float* out = (float*)d_out;

    size_t need = (size_t)X2ELEMS_ * 2 + (size_t)X2TELEMS_ * 2;  // 67.3 MB
    if (ws_size >= need) {
        unsigned short* X2  = (unsigned short*)d_ws;             // 33.6 MB
        unsigned short* x2T = X2 + X2ELEMS_;                     // 33.7 MB
        pack_x_k<<<dim3(64, 16), dim3(256), 0, stream>>>(x, x2T);
        legendre5_k<<<dim3(1056), dim3(256), 0, stream>>>(x2T, pct, X2);
        synth5_k<<<dim3(NLAT_, 2), dim3(256), 0, stream>>>(X2, out);
    } else {
        float* X = (float*)d_ws;
        legendre_k<<<dim3(2, MMAX_, 2), dim3(256), 0, stream>>>(x, pct, X);
        synth2_k<<<dim3(NLAT_, 2, 2), dim3(256), 0, stream>>>(X, out);
    }
}